// Round 5
// baseline (285.764 us; speedup 1.0000x reference)
//
#include <hip/hip_runtime.h>
#include <hip/hip_bf16.h>

typedef __attribute__((ext_vector_type(8))) short short8;
typedef __attribute__((ext_vector_type(4))) float floatx4;

#define NN     4096
#define DIN    128
#define EDIM   192
#define DMODEL 128

__device__ __forceinline__ unsigned short f2bf(float f) {
    union { float f; unsigned int i; } x; x.f = f;
    unsigned int u = x.i;
    u += 0x7FFFu + ((u >> 16) & 1u);   // RNE
    return (unsigned short)(u >> 16);
}

__device__ __forceinline__ unsigned int pk2(float lo, float hi) {
    union { __hip_bfloat162 v; unsigned int u; } cv;
    cv.v = __float22bfloat162_rn(make_float2(lo, hi));
    return cv.u;
}

__device__ __forceinline__ short8 cvt8(const float4 a, const float4 b) {
    union { short8 s; unsigned int u[4]; } r;
    r.u[0] = pk2(a.x, a.y);
    r.u[1] = pk2(a.z, a.w);
    r.u[2] = pk2(b.x, b.y);
    r.u[3] = pk2(b.z, b.w);
    return r.s;
}

// Pack W (576x128 fp32, row-major, original k = 3c+j feat / 384+e edge) into
// bf16 MFMA B-fragment order under PERMUTED k-order kt = j*128+c (feat), kt=k (edge):
// wf[((gs*8+ct)*64+lane)*8+jj] = bf16(W[korig(kt)*128 + ct*16 + (lane&15)]),
// kt = gs*32 + (lane>>4)*8 + jj.
__global__ void prep_w(const float* __restrict__ W, unsigned short* __restrict__ wf) {
    const int t = blockIdx.x * 256 + threadIdx.x;      // 288*256 == 73728 exactly
    const int jj   = t & 7;
    const int lane = (t >> 3) & 63;
    const int ct   = (t >> 9) & 7;
    const int gs   = t >> 12;
    const int kt = gs * 32 + ((lane >> 4) << 3) + jj;
    const int korig = (kt < 384) ? ((kt & 127) * 3 + (kt >> 7)) : kt;
    const int n = ct * 16 + (lane & 15);
    wf[t] = f2bf(W[korig * DMODEL + n]);
}

// Fused main kernel, BARRIER-FREE main loop. 512 blocks x 4 waves; block owns
// 128 rows x 128 cols of batch b. All operands (B fragments from L2-resident
// wfrag, A rows, adj chunks) are per-wave register rings with ISSUE DISTANCE 2:
// issued at stage s, consumed at stage s+2 (~2 stage-times of latency slack).
// No __syncthreads in the loop -> no collective vmcnt(0) drains; the compiler
// inserts counted vmcnt waits at each consumption point, so the memory queue
// never empties (the Round-4 sawtooth). adj passthrough stays interleaved.
__global__ __launch_bounds__(256, 2) void main_k(
    const float* __restrict__ feat,
    const float* __restrict__ edgef,
    const unsigned short* __restrict__ wfrag,
    const float* __restrict__ bias,
    const float* __restrict__ mask,
    const floatx4* __restrict__ adj4,
    floatx4* __restrict__ o_adj4,
    float* __restrict__ o_res,
    float* __restrict__ o_out,
    float* __restrict__ o_m)
{
    __shared__ float m3s[128];

    const int tid  = threadIdx.x;
    const int lane = tid & 63;
    const int wv   = tid >> 6;
    const int nn   = lane & 15;
    const int quad = lane >> 4;

    const int blk = blockIdx.x;
    const int b   = blk >> 5;                 // batch 0..15
    const int i0  = (blk & 31) << 7;          // 128-row tile base
    const int p   = b & 3;

    const float* fb = feat  + (size_t)b * NN * DIN;
    const float* eb = edgef + (size_t)b * NN * EDIM;
    const int rowb = i0 + wv * 32 + nn;       // A-row base (second tile adds 16)
    const int adjbase = blk * 256 + tid;      // adj chunk c at adjbase + c*131072

    // ---- m3 (3-window mask max) into LDS; blocks b<4 also emit output 3 ----
    if (tid < 128) {
        const int i = i0 + tid;
        float v = mask[p * NN + i];
        if (i + 1 < NN) v = fmaxf(v, mask[p * NN + i + 1]);
        if (i + 2 < NN) v = fmaxf(v, mask[p * NN + i + 2]);
        m3s[tid] = v;
        if (b < 4) o_m[p * NN + i] = v;
    }
    __syncthreads();                          // only barrier: m3s visibility

    const short8* wf8 = (const short8*)wfrag;
    const float4 zf4 = make_float4(0.f, 0.f, 0.f, 0.f);

    // ---- register rings (distance-2 pipeline) ----
    float4  Ar[2][4];                         // A rows: [ring][2 rows x 2 float4]
    short8  Br[2][8];                         // B fragments
    floatx4 Ja[2], Jb[2];                     // adj chunk pairs

    auto loadB = [&](int s, short8* B) {
        #pragma unroll
        for (int ct = 0; ct < 8; ++ct)
            B[ct] = wf8[(s * 8 + ct) * 64 + lane];
    };

    auto loadA = [&](int s, float4* A) {
        if (s < 12) {                         // feature region: j = s>>2, sl = s&3
            const int j = s >> 2, sl = s & 3;
            const int off = sl * 32 + quad * 8;
            const int r0 = rowb + j;
            A[0] = zf4; A[1] = zf4;
            if (r0 < NN) {
                const float* sp = fb + (size_t)r0 * DIN + off;
                A[0] = *(const float4*)sp; A[1] = *(const float4*)(sp + 4);
            }
            const int r1 = rowb + 16 + j;
            A[2] = zf4; A[3] = zf4;
            if (r1 < NN) {
                const float* sp = fb + (size_t)r1 * DIN + off;
                A[2] = *(const float4*)sp; A[3] = *(const float4*)(sp + 4);
            }
        } else {                              // edge region: eg = s-12; rows < NN always
            const int eg = s - 12;
            const int off = eg * 32 + quad * 8;
            const float* sp0 = eb + (size_t)rowb * EDIM + off;
            A[0] = *(const float4*)sp0; A[1] = *(const float4*)(sp0 + 4);
            const float* sp1 = eb + (size_t)(rowb + 16) * EDIM + off;
            A[2] = *(const float4*)sp1; A[3] = *(const float4*)(sp1 + 4);
        }
    };

    floatx4 acc[2][8];
    #pragma unroll
    for (int rt = 0; rt < 2; ++rt)
        #pragma unroll
        for (int ct = 0; ct < 8; ++ct)
            acc[rt][ct] = (floatx4){0.f, 0.f, 0.f, 0.f};

    // ---- prologue: fill both ring slots (stages 0 and 1) ----
    loadB(0, Br[0]);
    loadB(1, Br[1]);
    loadA(0, Ar[0]);
    loadA(1, Ar[1]);
    Ja[0] = __builtin_nontemporal_load(&adj4[adjbase]);
    Jb[0] = __builtin_nontemporal_load(&adj4[adjbase + (size_t)1 * 131072]);
    Ja[1] = __builtin_nontemporal_load(&adj4[adjbase + (size_t)2 * 131072]);
    Jb[1] = __builtin_nontemporal_load(&adj4[adjbase + (size_t)3 * 131072]);

    // ---- 18-stage barrier-free main loop (12 feature + 6 edge) ----
    #pragma unroll
    for (int s = 0; s < 18; ++s) {
        const int pr = s & 1;

        // consume A(s) (compiler inserts counted vmcnt before first use)
        const short8 af0 = cvt8(Ar[pr][0], Ar[pr][1]);
        const short8 af1 = cvt8(Ar[pr][2], Ar[pr][3]);

        // adj: store pair(s) (loaded at s-2), reissue pair(s+2) into same slot
        if (s <= 15) {
            __builtin_nontemporal_store(Ja[pr], &o_adj4[adjbase + (size_t)(2 * s) * 131072]);
            __builtin_nontemporal_store(Jb[pr], &o_adj4[adjbase + (size_t)(2 * s + 1) * 131072]);
        }
        if (s <= 13) {
            Ja[pr] = __builtin_nontemporal_load(&adj4[adjbase + (size_t)(2 * s + 4) * 131072]);
            Jb[pr] = __builtin_nontemporal_load(&adj4[adjbase + (size_t)(2 * s + 5) * 131072]);
        }

        // bind B(s) to temps (SSA rename), then reissue ring slot with s+2
        short8 bt[8];
        #pragma unroll
        for (int ct = 0; ct < 8; ++ct)
            bt[ct] = Br[pr][ct];
        if (s <= 15) {
            loadB(s + 2, Br[pr]);
            loadA(s + 2, Ar[pr]);
        }

        #pragma unroll
        for (int ct = 0; ct < 8; ++ct) {
            acc[0][ct] = __builtin_amdgcn_mfma_f32_16x16x32_bf16(af0, bt[ct], acc[0][ct], 0, 0, 0);
            acc[1][ct] = __builtin_amdgcn_mfma_f32_16x16x32_bf16(af1, bt[ct], acc[1][ct], 0, 0, 0);
        }
    }

    // ---- epilogue: bias + ReLU, jump (3-row feature mean), mask, fp32 stores ----
    float biasv[8];
    #pragma unroll
    for (int ct = 0; ct < 8; ++ct)
        biasv[ct] = bias[ct * 16 + nn];

    const float inv3 = 1.0f / 3.0f;

    #pragma unroll
    for (int rt = 0; rt < 2; ++rt) {
        const int rbase = wv * 32 + rt * 16 + quad * 4;   // C/D: row = quad*4 + reg
        float mv[4];
        #pragma unroll
        for (int reg = 0; reg < 4; ++reg)
            mv[reg] = m3s[rbase + reg];
        #pragma unroll
        for (int ct = 0; ct < 8; ++ct) {
            const int col = ct * 16 + nn;                 // C/D: col = lane&15
            float fv[6];
            #pragma unroll
            for (int t6 = 0; t6 < 6; ++t6) {
                const int row = i0 + rbase + t6;
                fv[t6] = (row < NN) ? fb[(size_t)row * DIN + col] : 0.f;
            }
            #pragma unroll
            for (int reg = 0; reg < 4; ++reg) {
                float o = acc[rt][ct][reg] + biasv[ct];
                o = fmaxf(o, 0.f);
                const float jmp = (fv[reg] + fv[reg + 1] + fv[reg + 2]) * inv3;
                const size_t off = ((size_t)b * NN + (i0 + rbase + reg)) * DMODEL + col;
                const float mm = mv[reg];
                __builtin_nontemporal_store(mm * o, &o_out[off]);
                __builtin_nontemporal_store(mm * (o + jmp), &o_res[off]);
            }
        }
    }
}

extern "C" void kernel_launch(void* const* d_in, const int* in_sizes, int n_in,
                              void* d_out, int out_size, void* d_ws, size_t ws_size,
                              hipStream_t stream) {
    const float* adj   = (const float*)d_in[0];
    const float* feat  = (const float*)d_in[1];
    const float* edgef = (const float*)d_in[2];
    const float* mask  = (const float*)d_in[3];
    const float* W     = (const float*)d_in[4];
    const float* bias  = (const float*)d_in[5];

    float* out   = (float*)d_out;
    float* o_adj = out;
    float* o_res = out + (size_t)16777216;              // 4096*4096
    float* o_out = o_res + (size_t)8388608;             // 16*4096*128
    float* o_m   = o_out + (size_t)8388608;             // + 16*4096*128 -> 4*4096 tail

    unsigned short* wfrag = (unsigned short*)d_ws;      // 73728 * 2 B

    prep_w<<<288, 256, 0, stream>>>(W, wfrag);
    main_k<<<512, 256, 0, stream>>>(feat, edgef, wfrag, bias, mask,
                                    (const floatx4*)adj, (floatx4*)o_adj,
                                    o_res, o_out, o_m);
}

// Round 7
// 267.126 us; speedup vs baseline: 1.0698x; 1.0698x over previous
//
#include <hip/hip_runtime.h>
#include <hip/hip_bf16.h>

typedef __attribute__((ext_vector_type(8))) short short8;
typedef __attribute__((ext_vector_type(4))) float floatx4;

#define NN     4096
#define DIN    128
#define EDIM   192
#define DMODEL 128

__device__ __forceinline__ unsigned short f2bf(float f) {
    union { float f; unsigned int i; } x; x.f = f;
    unsigned int u = x.i;
    u += 0x7FFFu + ((u >> 16) & 1u);   // RNE
    return (unsigned short)(u >> 16);
}

__device__ __forceinline__ unsigned int pk2(float lo, float hi) {
    union { __hip_bfloat162 v; unsigned int u; } cv;
    cv.v = __float22bfloat162_rn(make_float2(lo, hi));
    return cv.u;
}

__device__ __forceinline__ short8 cvt8(const float4 a, const float4 b) {
    union { short8 s; unsigned int u[4]; } r;
    r.u[0] = pk2(a.x, a.y);
    r.u[1] = pk2(a.z, a.w);
    r.u[2] = pk2(b.x, b.y);
    r.u[3] = pk2(b.z, b.w);
    return r.s;
}

// async 16B global->LDS copy; LDS dest is wave-uniform base + lane*16 (HW adds).
__device__ __forceinline__ void gl_lds16(const void* g, void* l) {
    __builtin_amdgcn_global_load_lds(
        (const __attribute__((address_space(1))) unsigned int*)g,
        (__attribute__((address_space(3))) unsigned int*)l,
        16, 0, 0);
}

// Pack W (576x128 fp32, row-major, original k = 3c+j feat / 384+e edge) into
// bf16 MFMA B-fragment order under PERMUTED k-order kt = j*128+c (feat), kt=k (edge):
// wf[((gs*8+ct)*64+lane)*8+jj] = bf16(W[korig(kt)*128 + ct*16 + (lane&15)]),
// kt = gs*32 + (lane>>4)*8 + jj.
__global__ void prep_w(const float* __restrict__ W, unsigned short* __restrict__ wf) {
    const int t = blockIdx.x * 256 + threadIdx.x;      // 288*256 == 73728 exactly
    const int jj   = t & 7;
    const int lane = (t >> 3) & 63;
    const int ct   = (t >> 9) & 7;
    const int gs   = t >> 12;
    const int kt = gs * 32 + ((lane >> 4) << 3) + jj;
    const int korig = (kt < 384) ? ((kt & 127) * 3 + (kt >> 7)) : kt;
    const int n = ct * 16 + (lane & 15);
    wf[t] = f2bf(W[korig * DMODEL + n]);
}

// Fused main kernel with a COUNTED-VMCNT pipeline (T3/T4). 512 blocks x 4
// waves; block owns 128 rows x 128 cols of batch b. B fragments are DMA'd
// into a 4-deep LDS ring, issued 3 stages ahead; A rows distance-1 in regs;
// adj passthrough interleaved at distance 2. Raw s_barrier per stage with a
// hand-counted s_waitcnt vmcnt(N) (never 0) so the memory queue never
// empties. vmem issue order is pinned with sched_barrier(0) fences; A-loads
// are exec-uniform (clamp+cndmask, no divergent branch) so per-wave vmcnt
// counts are identical across waves.
__global__ __launch_bounds__(256, 2) void main_k(
    const float* __restrict__ feat,
    const float* __restrict__ edgef,
    const unsigned short* __restrict__ wfrag,
    const float* __restrict__ bias,
    const float* __restrict__ mask,
    const floatx4* __restrict__ adj4,
    floatx4* __restrict__ o_adj4,
    float* __restrict__ o_res,
    float* __restrict__ o_out,
    float* __restrict__ o_m)
{
    __shared__ __align__(16) char lbuf[4][8192];   // B-fragment 4-deep ring
    __shared__ float m3s[128];

    const int tid  = threadIdx.x;
    const int lane = tid & 63;
    const int wv   = tid >> 6;
    const int nn   = lane & 15;
    const int quad = lane >> 4;

    const int blk = blockIdx.x;
    const int b   = blk >> 5;                 // batch 0..15
    const int i0  = (blk & 31) << 7;          // 128-row tile base
    const int p   = b & 3;

    const float* fb = feat  + (size_t)b * NN * DIN;
    const float* eb = edgef + (size_t)b * NN * EDIM;
    const int rowb = i0 + wv * 32 + nn;       // A-row base (second tile adds 16)
    const int adjbase = blk * 256 + tid;      // adj chunk c at adjbase + c*131072

    // ---- m3 (3-window mask max) into LDS; blocks b<4 also emit output 3 ----
    if (tid < 128) {
        const int i = i0 + tid;
        float v = mask[p * NN + i];
        if (i + 1 < NN) v = fmaxf(v, mask[p * NN + i + 1]);
        if (i + 2 < NN) v = fmaxf(v, mask[p * NN + i + 2]);
        m3s[tid] = v;
        if (b < 4) o_m[p * NN + i] = v;
    }

    const char* wsrc = (const char*)wfrag;
    const float4 zf4 = make_float4(0.f, 0.f, 0.f, 0.f);

    auto stageB = [&](int s) {                // DMA 8KB stage s into ring slot s&3
        const char* src = wsrc + s * 8192 + wv * 2048 + lane * 16;
        char* dst = &lbuf[s & 3][wv * 2048];
        gl_lds16(src, dst);
        gl_lds16(src + 1024, dst + 1024);
    };

    // exec-uniform A loads: 4 vmem ops always, no divergent branches.
    auto loadA = [&](int s, float4* A) {
        if (s < 12) {                         // feature region: j = s>>2, sl = s&3
            const int j = s >> 2, sl = s & 3;
            const int off = sl * 32 + quad * 8;
            const float* sp0 = fb + (size_t)(rowb + j) * DIN + off;   // always < NN
            A[0] = *(const float4*)sp0; A[1] = *(const float4*)(sp0 + 4);
            const int r1 = rowb + 16 + j;                             // may be >= NN
            const int r1c = (r1 < NN) ? r1 : (NN - 1);
            const float* sp1 = fb + (size_t)r1c * DIN + off;
            const float4 v0 = *(const float4*)sp1;
            const float4 v1 = *(const float4*)(sp1 + 4);
            A[2] = (r1 < NN) ? v0 : zf4;      // per-lane cndmask, no branch
            A[3] = (r1 < NN) ? v1 : zf4;
        } else {                              // edge region: rows always < NN
            const int eg = s - 12;
            const int off = eg * 32 + quad * 8;
            const float* sp0 = eb + (size_t)rowb * EDIM + off;
            A[0] = *(const float4*)sp0; A[1] = *(const float4*)(sp0 + 4);
            const float* sp1 = eb + (size_t)(rowb + 16) * EDIM + off;
            A[2] = *(const float4*)sp1; A[3] = *(const float4*)(sp1 + 4);
        }
    };

    floatx4 acc[2][8];
    #pragma unroll
    for (int rt = 0; rt < 2; ++rt)
        #pragma unroll
        for (int ct = 0; ct < 8; ++ct)
            acc[rt][ct] = (floatx4){0.f, 0.f, 0.f, 0.f};

    float4  Ar[2][4];                         // A distance-1 double set
    floatx4 Ja[2], Jb[2];                     // adj pairs, distance-2

    // ---- prologue: adj pairs 0,1; A(0); then DMA stages 0,1,2 (last) ----
    Ja[0] = __builtin_nontemporal_load(&adj4[adjbase]);
    Jb[0] = __builtin_nontemporal_load(&adj4[adjbase + (size_t)1 * 131072]);
    Ja[1] = __builtin_nontemporal_load(&adj4[adjbase + (size_t)2 * 131072]);
    Jb[1] = __builtin_nontemporal_load(&adj4[adjbase + (size_t)3 * 131072]);
    loadA(0, Ar[0]);
    __builtin_amdgcn_sched_barrier(0);
    stageB(0); stageB(1); stageB(2);
    // DMA0 retired when <=4 outstanding (only DMA1,DMA2 newer); lgkmcnt(0) for m3s.
    asm volatile("s_waitcnt vmcnt(4) lgkmcnt(0)" ::: "memory");
    __builtin_amdgcn_s_barrier();

    // Stage s vmem order: [adjS(s), adjL(s+2), A(s+1)] | DMA(s+3) | MFMA |
    // wait vmcnt(NW) + barrier.  NW(s) = ops issued after DMA(s+1):
    // t(sig)=a+b+d+c with a=2 (s<=15), b=2 (s<=13), d=4 (s<=16), c=2 (s<=14);
    // s=0: DMA(1) in prologue -> DMA2(2)+t(0)=12. s=1: t(0)+t(1)=20.
    // s=2..13: 20. s=14: t(13)+t(14)=18. s=15: t(14)+t(15)=14. s=16: 10.
#define STAGE(S, NW)                                                                         \
    {                                                                                        \
        constexpr int s = (S);                                                               \
        constexpr int pr = s & 1;                                                            \
        if (s <= 15) {                                                                       \
            __builtin_nontemporal_store(Ja[pr], &o_adj4[adjbase + (size_t)(2 * s) * 131072]);     \
            __builtin_nontemporal_store(Jb[pr], &o_adj4[adjbase + (size_t)(2 * s + 1) * 131072]); \
        }                                                                                    \
        if (s <= 13) {                                                                       \
            Ja[pr] = __builtin_nontemporal_load(&adj4[adjbase + (size_t)(2 * s + 4) * 131072]);   \
            Jb[pr] = __builtin_nontemporal_load(&adj4[adjbase + (size_t)(2 * s + 5) * 131072]);   \
        }                                                                                    \
        if (s <= 16) loadA(s + 1, Ar[(s + 1) & 1]);                                          \
        __builtin_amdgcn_sched_barrier(0);                                                   \
        if (s <= 14) stageB(s + 3);                                                          \
        __builtin_amdgcn_sched_barrier(0);                                                   \
        {                                                                                    \
            const short8* bl = (const short8*)(&lbuf[s & 3][0]);                             \
            const short8 af0 = cvt8(Ar[pr][0], Ar[pr][1]);                                   \
            const short8 af1 = cvt8(Ar[pr][2], Ar[pr][3]);                                   \
            _Pragma("unroll")                                                                \
            for (int ct = 0; ct < 8; ++ct) {                                                 \
                const short8 bfr = bl[ct * 64 + lane];                                       \
                acc[0][ct] = __builtin_amdgcn_mfma_f32_16x16x32_bf16(af0, bfr, acc[0][ct], 0, 0, 0); \
                acc[1][ct] = __builtin_amdgcn_mfma_f32_16x16x32_bf16(af1, bfr, acc[1][ct], 0, 0, 0); \
            }                                                                                \
        }                                                                                    \
        if (s < 17) {                                                                        \
            asm volatile("s_waitcnt vmcnt(" #NW ")" ::: "memory");                           \
            __builtin_amdgcn_s_barrier();                                                    \
        }                                                                                    \
    }

    STAGE(0, 12)
    STAGE(1, 20)
    STAGE(2, 20)
    STAGE(3, 20)
    STAGE(4, 20)
    STAGE(5, 20)
    STAGE(6, 20)
    STAGE(7, 20)
    STAGE(8, 20)
    STAGE(9, 20)
    STAGE(10, 20)
    STAGE(11, 20)
    STAGE(12, 20)
    STAGE(13, 20)
    STAGE(14, 18)
    STAGE(15, 14)
    STAGE(16, 10)
    STAGE(17, 0)
#undef STAGE

    // ---- epilogue: bias + ReLU, jump (3-row feature mean), mask, fp32 stores ----
    float biasv[8];
    #pragma unroll
    for (int ct = 0; ct < 8; ++ct)
        biasv[ct] = bias[ct * 16 + nn];

    const float inv3 = 1.0f / 3.0f;

    #pragma unroll
    for (int rt = 0; rt < 2; ++rt) {
        const int rbase = wv * 32 + rt * 16 + quad * 4;   // C/D: row = quad*4 + reg
        float mv[4];
        #pragma unroll
        for (int reg = 0; reg < 4; ++reg)
            mv[reg] = m3s[rbase + reg];
        #pragma unroll
        for (int ct = 0; ct < 8; ++ct) {
            const int col = ct * 16 + nn;                 // C/D: col = lane&15
            float fv[6];
            #pragma unroll
            for (int t6 = 0; t6 < 6; ++t6) {
                const int row = i0 + rbase + t6;
                fv[t6] = (row < NN) ? fb[(size_t)row * DIN + col] : 0.f;
            }
            #pragma unroll
            for (int reg = 0; reg < 4; ++reg) {
                float o = acc[rt][ct][reg] + biasv[ct];
                o = fmaxf(o, 0.f);
                const float jmp = (fv[reg] + fv[reg + 1] + fv[reg + 2]) * inv3;
                const size_t off = ((size_t)b * NN + (i0 + rbase + reg)) * DMODEL + col;
                const float mm = mv[reg];
                __builtin_nontemporal_store(mm * o, &o_out[off]);
                __builtin_nontemporal_store(mm * (o + jmp), &o_res[off]);
            }
        }
    }
}

extern "C" void kernel_launch(void* const* d_in, const int* in_sizes, int n_in,
                              void* d_out, int out_size, void* d_ws, size_t ws_size,
                              hipStream_t stream) {
    const float* adj   = (const float*)d_in[0];
    const float* feat  = (const float*)d_in[1];
    const float* edgef = (const float*)d_in[2];
    const float* mask  = (const float*)d_in[3];
    const float* W     = (const float*)d_in[4];
    const float* bias  = (const float*)d_in[5];

    float* out   = (float*)d_out;
    float* o_adj = out;
    float* o_res = out + (size_t)16777216;              // 4096*4096
    float* o_out = o_res + (size_t)8388608;             // 16*4096*128
    float* o_m   = o_out + (size_t)8388608;             // + 16*4096*128 -> 4*4096 tail

    unsigned short* wfrag = (unsigned short*)d_ws;      // 73728 * 2 B

    prep_w<<<288, 256, 0, stream>>>(W, wfrag);
    main_k<<<512, 256, 0, stream>>>(feat, edgef, wfrag, bias, mask,
                                    (const floatx4*)adj, (floatx4*)o_adj,
                                    o_res, o_out, o_m);
}

// Round 8
// 267.006 us; speedup vs baseline: 1.0703x; 1.0004x over previous
//
#include <hip/hip_runtime.h>
#include <hip/hip_bf16.h>

typedef __attribute__((ext_vector_type(8))) short short8;
typedef __attribute__((ext_vector_type(4))) float floatx4;

#define NN     4096
#define DIN    128
#define EDIM   192
#define DMODEL 128

__device__ __forceinline__ unsigned short f2bf(float f) {
    union { float f; unsigned int i; } x; x.f = f;
    unsigned int u = x.i;
    u += 0x7FFFu + ((u >> 16) & 1u);   // RNE
    return (unsigned short)(u >> 16);
}

__device__ __forceinline__ unsigned int pk2(float lo, float hi) {
    union { __hip_bfloat162 v; unsigned int u; } cv;
    cv.v = __float22bfloat162_rn(make_float2(lo, hi));
    return cv.u;
}

__device__ __forceinline__ short8 cvt8(const float4 a, const float4 b) {
    union { short8 s; unsigned int u[4]; } r;
    r.u[0] = pk2(a.x, a.y);
    r.u[1] = pk2(a.z, a.w);
    r.u[2] = pk2(b.x, b.y);
    r.u[3] = pk2(b.z, b.w);
    return r.s;
}

// async 16B global->LDS copy; LDS dest is wave-uniform base + lane*16 (HW adds).
__device__ __forceinline__ void gl_lds16(const void* g, void* l) {
    __builtin_amdgcn_global_load_lds(
        (const __attribute__((address_space(1))) unsigned int*)g,
        (__attribute__((address_space(3))) unsigned int*)l,
        16, 0, 0);
}

// Pack W (576x128 fp32, row-major, original k = 3c+j feat / 384+e edge) into
// bf16 MFMA B-fragment order under PERMUTED k-order kt = j*128+c (feat), kt=k (edge):
// wf[((gs*8+ct)*64+lane)*8+jj] = bf16(W[korig(kt)*128 + ct*16 + (lane&15)]),
// kt = gs*32 + (lane>>4)*8 + jj.
__global__ void prep_w(const float* __restrict__ W, unsigned short* __restrict__ wf) {
    const int t = blockIdx.x * 256 + threadIdx.x;      // 288*256 == 73728 exactly
    const int jj   = t & 7;
    const int lane = (t >> 3) & 63;
    const int ct   = (t >> 9) & 7;
    const int gs   = t >> 12;
    const int kt = gs * 32 + ((lane >> 4) << 3) + jj;
    const int korig = (kt < 384) ? ((kt & 127) * 3 + (kt >> 7)) : kt;
    const int n = ct * 16 + (lane & 15);
    wf[t] = f2bf(W[korig * DMODEL + n]);
}

// Fused main kernel, HIGH-OCCUPANCY variant: 512 blocks x 512 threads
// (8 waves). Block owns 128 rows x 128 cols of batch b; each wave one 16-row
// MFMA tile (acc[8]). 16 waves/CU (4 waves/SIMD, 2 blocks/CU) doubles the
// per-CU memory parallelism vs the 8-wave/CU predecessors, which plateaued
// at ~85us / 3.0 TB/s across three scheduling structures (latency-limited).
// B fragments DMA'd to LDS double-buffer (1KB/wave/stage); A distance-1 in
// regs; adj passthrough interleaved (1 chunk/thread/stage, 16 total).
__global__ __launch_bounds__(512, 4) void main_k(
    const float* __restrict__ feat,
    const float* __restrict__ edgef,
    const unsigned short* __restrict__ wfrag,
    const float* __restrict__ bias,
    const float* __restrict__ mask,
    const floatx4* __restrict__ adj4,
    floatx4* __restrict__ o_adj4,
    float* __restrict__ o_res,
    float* __restrict__ o_out,
    float* __restrict__ o_m)
{
    __shared__ __align__(16) char lbuf[2][8192];   // B-fragment double buffer
    __shared__ float m3s[128];

    const int tid  = threadIdx.x;
    const int lane = tid & 63;
    const int wv   = tid >> 6;                // 0..7
    const int nn   = lane & 15;
    const int quad = lane >> 4;

    const int blk = blockIdx.x;
    const int b   = blk >> 5;                 // batch 0..15
    const int i0  = (blk & 31) << 7;          // 128-row tile base
    const int p   = b & 3;

    const float* fb = feat  + (size_t)b * NN * DIN;
    const float* eb = edgef + (size_t)b * NN * EDIM;
    const int rowb = i0 + wv * 16 + nn;       // A-row for this lane
    const int adjbase = blk * 512 + tid;      // adj chunk c at adjbase + c*262144

    // ---- m3 (3-window mask max) into LDS; blocks b<4 also emit output 3 ----
    if (tid < 128) {
        const int i = i0 + tid;
        float v = mask[p * NN + i];
        if (i + 1 < NN) v = fmaxf(v, mask[p * NN + i + 1]);
        if (i + 2 < NN) v = fmaxf(v, mask[p * NN + i + 2]);
        m3s[tid] = v;
        if (b < 4) o_m[p * NN + i] = v;
    }

    // ---- stage/prefetch helpers ----
    const char* wsrc = (const char*)wfrag;

    auto stageB = [&](int s, int bi) {
        // copy 8KB stage s of W-fragments into lbuf[bi]; wave wv covers 1KB.
        const char* src = wsrc + s * 8192 + wv * 1024 + lane * 16;
        char* dst = &lbuf[bi][wv * 1024];
        gl_lds16(src, dst);
    };

    const float4 zf4 = make_float4(0.f, 0.f, 0.f, 0.f);

    auto loadA = [&](int s, float4& a0, float4& a1) {
        if (s < 12) {                         // feature region: j = s>>2, sl = s&3
            const int j = s >> 2, sl = s & 3;
            const int off = sl * 32 + quad * 8;
            const int r = rowb + j;
            a0 = zf4; a1 = zf4;
            if (r < NN) {
                const float* sp = fb + (size_t)r * DIN + off;
                a0 = *(const float4*)sp; a1 = *(const float4*)(sp + 4);
            }
        } else {                              // edge region: rows always < NN
            const int eg = s - 12;
            const int off = eg * 32 + quad * 8;
            const float* sp = eb + (size_t)rowb * EDIM + off;
            a0 = *(const float4*)sp; a1 = *(const float4*)(sp + 4);
        }
    };

    floatx4 acc[8];
    #pragma unroll
    for (int ct = 0; ct < 8; ++ct)
        acc[ct] = (floatx4){0.f, 0.f, 0.f, 0.f};

    // ---- prologue: B(0) via DMA, A(0) in regs, adj chunk 0 in flight ----
    float4 a0, a1, n0, n1;
    floatx4 Jcur, Jnxt;
    stageB(0, 0);
    loadA(0, a0, a1);
    Jcur = __builtin_nontemporal_load(&adj4[adjbase]);
    __syncthreads();                          // drains vmcnt: buf0 + A(0) + chunk0

    // ---- 18-stage main loop (12 feature + 6 edge), adj interleaved ----
    #pragma unroll
    for (int s = 0; s < 18; ++s) {
        const int cur = s & 1;

        // adj: store chunk s (arrived via previous barrier's drain), load s+1
        if (s <= 15)
            __builtin_nontemporal_store(Jcur, &o_adj4[adjbase + (size_t)s * 262144]);
        if (s <= 14)
            Jnxt = __builtin_nontemporal_load(&adj4[adjbase + (size_t)(s + 1) * 262144]);

        if (s < 17) {
            stageB(s + 1, cur ^ 1);           // DMA next B stage into other buffer
            loadA(s + 1, n0, n1);             // prefetch next A into regs
        }

        const short8* bl = (const short8*)(&lbuf[cur][0]);
        const short8 af = cvt8(a0, a1);
        #pragma unroll
        for (int ct = 0; ct < 8; ++ct)
            acc[ct] = __builtin_amdgcn_mfma_f32_16x16x32_bf16(af, bl[ct * 64 + lane], acc[ct], 0, 0, 0);

        a0 = n0; a1 = n1; Jcur = Jnxt;
        if (s < 17) __syncthreads();          // reads of cur done; DMA+A+adj drained
    }

    // ---- epilogue: bias + ReLU, jump (3-row feature mean), mask, fp32 stores ----
    float biasv[8];
    #pragma unroll
    for (int ct = 0; ct < 8; ++ct)
        biasv[ct] = bias[ct * 16 + nn];

    const float inv3 = 1.0f / 3.0f;
    const int rbase = wv * 16 + quad * 4;     // C/D: row = quad*4 + reg
    float mv[4];
    #pragma unroll
    for (int reg = 0; reg < 4; ++reg)
        mv[reg] = m3s[rbase + reg];

    #pragma unroll
    for (int ct = 0; ct < 8; ++ct) {
        const int col = ct * 16 + nn;         // C/D: col = lane&15
        float fv[6];
        #pragma unroll
        for (int t6 = 0; t6 < 6; ++t6) {
            const int row = i0 + rbase + t6;
            fv[t6] = (row < NN) ? fb[(size_t)row * DIN + col] : 0.f;
        }
        #pragma unroll
        for (int reg = 0; reg < 4; ++reg) {
            float o = acc[ct][reg] + biasv[ct];
            o = fmaxf(o, 0.f);
            const float jmp = (fv[reg] + fv[reg + 1] + fv[reg + 2]) * inv3;
            const size_t off = ((size_t)b * NN + (i0 + rbase + reg)) * DMODEL + col;
            const float mm = mv[reg];
            __builtin_nontemporal_store(mm * o, &o_out[off]);
            __builtin_nontemporal_store(mm * (o + jmp), &o_res[off]);
        }
    }
}

extern "C" void kernel_launch(void* const* d_in, const int* in_sizes, int n_in,
                              void* d_out, int out_size, void* d_ws, size_t ws_size,
                              hipStream_t stream) {
    const float* adj   = (const float*)d_in[0];
    const float* feat  = (const float*)d_in[1];
    const float* edgef = (const float*)d_in[2];
    const float* mask  = (const float*)d_in[3];
    const float* W     = (const float*)d_in[4];
    const float* bias  = (const float*)d_in[5];

    float* out   = (float*)d_out;
    float* o_adj = out;
    float* o_res = out + (size_t)16777216;              // 4096*4096
    float* o_out = o_res + (size_t)8388608;             // 16*4096*128
    float* o_m   = o_out + (size_t)8388608;             // + 16*4096*128 -> 4*4096 tail

    unsigned short* wfrag = (unsigned short*)d_ws;      // 73728 * 2 B

    prep_w<<<288, 256, 0, stream>>>(W, wfrag);
    main_k<<<512, 512, 0, stream>>>(feat, edgef, wfrag, bias, mask,
                                    (const floatx4*)adj, (floatx4*)o_adj,
                                    o_res, o_out, o_m);
}